// Round 7
// baseline (287.590 us; speedup 1.0000x reference)
//
#include <hip/hip_runtime.h>

// ---------------------------------------------------------------------------
// AttentionAugmentedConv2d: B=8, CIN=256, COUT=512, DK=DV=256, NH=8, H=W=32
//  k_xt     : x (fp32) -> padded transposed Xt[b][yy:34][xx:34][ci:256] bf16
//  k_wconv  : weights -> bf16, K reordered to k'=(ky*3+kx)*256+ci (wt)
//  k_gemm0  : implicit-GEMM fused conv (128M x 64N, BK=64, 1024 blocks)
//  k_attn   : MFMA flash attention v4: no online max, XCD-swizzled grid
//             (bid = qt*64+bh -> K/V L2-resident per XCD), software-pipelined
//             double-buffered P transpose; coalesced output attT [ci][m2]
//  k_tr     : attT [256][8192] -> attt [8192][256]
//  k_gemm_s : 1x1 conv GEMM -> out ch 256..511
// reshape trap: att channel = h*32 + y, spatial = (x, d)
// ---------------------------------------------------------------------------

typedef __attribute__((ext_vector_type(8))) short short8;
typedef __attribute__((ext_vector_type(4))) float floatx4;

__device__ __forceinline__ unsigned short f2bf(float f) {
    unsigned int u = __float_as_uint(f);
    u += 0x7FFFu + ((u >> 16) & 1u);   // round-to-nearest-even
    return (unsigned short)(u >> 16);
}
__device__ __forceinline__ float bf2f(unsigned short s) {
    return __uint_as_float(((unsigned int)s) << 16);
}
__device__ __forceinline__ unsigned int pk2bf_trunc(float lo, float hi) {
    return (__float_as_uint(lo) >> 16) | (__float_as_uint(hi) & 0xFFFF0000u);
}
__device__ __forceinline__ unsigned int pk2bf_rne(float lo, float hi) {
    return (unsigned int)f2bf(lo) | ((unsigned int)f2bf(hi) << 16);
}
__device__ __forceinline__ void gload_lds16(const unsigned short* g, unsigned short* s) {
    __builtin_amdgcn_global_load_lds(
        (const __attribute__((address_space(1))) unsigned int*)g,
        (__attribute__((address_space(3))) unsigned int*)s, 16, 0, 0);
}

// ---------------- Xt: padded transpose -------------------------------------
__global__ __launch_bounds__(256) void k_xt(const float* __restrict__ x,
                                            unsigned short* __restrict__ Xt) {
    __shared__ unsigned short lds[256 * 33];
    const int tid = threadIdx.x;
    const int yy = blockIdx.x % 34;
    const int b  = blockIdx.x / 34;
    unsigned int* outp = (unsigned int*)(Xt + (((size_t)b * 34 + yy) * 34) * 256);
    if (yy == 0 || yy == 33) {
        for (int i = tid; i < 4352; i += 256) outp[i] = 0;
        return;
    }
    const int y = yy - 1;
    const float* xb = x + (size_t)b * 262144 + y * 32;
#pragma unroll
    for (int it = 0; it < 32; ++it) {
        const int e = it * 256 + tid;
        const int ci = e >> 5, xx = e & 31;
        lds[ci * 33 + xx] = f2bf(xb[ci * 1024 + xx]);
    }
    __syncthreads();
    const int ci2 = (tid & 127) * 2;
    const int xh = tid >> 7;
#pragma unroll
    for (int it = 0; it < 17; ++it) {
        const int xx = xh * 17 + it;
        unsigned int v = 0;
        if (xx >= 1 && xx <= 32)
            v = (unsigned int)lds[ci2 * 33 + xx - 1] |
                ((unsigned int)lds[(ci2 + 1) * 33 + xx - 1] << 16);
        outp[xx * 128 + (tid & 127)] = v;
    }
}

// --------------- weight convert + K reorder, LDS-staged ---------------------
__global__ __launch_bounds__(256) void k_wconv(const float* __restrict__ wc,
                                               const float* __restrict__ wq,
                                               const float* __restrict__ wa,
                                               const float* __restrict__ krw,
                                               const float* __restrict__ krh,
                                               unsigned short* __restrict__ wt,
                                               unsigned short* __restrict__ wt2,
                                               unsigned short* __restrict__ krwb,
                                               unsigned short* __restrict__ krhb) {
    const int tid = threadIdx.x;
    const int blk = blockIdx.x;
    if (blk < 1024) {
        __shared__ float lw[2304];
        const int n = blk;
        const float* src = (n < 256) ? (wc + (size_t)n * 2304)
                                     : (wq + (size_t)(n - 256) * 2304);
#pragma unroll
        for (int it = 0; it < 9; ++it)
            lw[it * 256 + tid] = src[it * 256 + tid];
        __syncthreads();
#pragma unroll
        for (int it = 0; it < 9; ++it) {
            const int kp = it * 256 + tid;
            const int g = kp >> 8, ci = kp & 255;
            wt[(size_t)n * 2304 + kp] = f2bf(lw[ci * 9 + g]);
        }
    } else {
        const int i = (blk - 1024) * 256 + tid;
        if (i < 65536)        wt2[i] = f2bf(wa[i]);
        else if (i < 67584) { const int j = i - 65536;
                              krwb[j] = (j < 2016) ? f2bf(krw[j]) : (unsigned short)0; }
        else if (i < 69632) { const int j = i - 67584;
                              krhb[j] = (j < 2016) ? f2bf(krh[j]) : (unsigned short)0; }
    }
}

// --------------- implicit-GEMM fused conv, 128M x 64N, BK=64 ----------------
__global__ __launch_bounds__(256, 4) void k_gemm0(const unsigned short* __restrict__ Wr,
                                                  const unsigned short* __restrict__ Xt,
                                                  float* __restrict__ out,
                                                  unsigned short* __restrict__ qT,
                                                  unsigned short* __restrict__ kT,
                                                  unsigned short* __restrict__ vT,
                                                  const float* __restrict__ bias_a,
                                                  const float* __restrict__ bias_b) {
    __shared__ unsigned short As[64 * 64];
    __shared__ unsigned short Bs[128 * 64];
    const int tid = threadIdx.x;
    const int lane = tid & 63, wv = tid >> 6;
    const int l15 = lane & 15, quad = lane >> 4;
    const int m0 = blockIdx.x * 128, n0 = blockIdx.y * 64;
    const int wave_m = (wv & 1) * 64, wave_n = (wv >> 1) * 32;
    floatx4 acc[2][4] = {};
    const int lr = lane >> 3;
    const int swz8 = ((lane & 7) ^ lr) * 8;
    const unsigned short* gA = Wr + (size_t)(n0 + wv * 16 + lr) * 2304 + swz8;
    int bb0[4];
#pragma unroll
    for (int r = 0; r < 4; ++r) {
        const int m = m0 + wv * 32 + r * 8 + lr;
        const int b = m >> 10, p = m & 1023, y = p >> 5, x = p & 31;
        bb0[r] = ((b * 34 + y) * 34 + x) * 256;
    }
    unsigned short* sA0 = As + wv * 1024;
    unsigned short* sB0 = Bs + wv * 2048;
    const int sw0 = ((quad)     ^ (l15 & 7)) * 8;
    const int sw1 = ((4 + quad) ^ (l15 & 7)) * 8;
    for (int k0 = 0; k0 < 2304; k0 += 64) {
        const int g = k0 >> 8;
        const int ci0 = k0 & 255;
        const int ky = g / 3, kx = g - ky * 3;
        const int offu = (ky * 34 + kx) * 256 + ci0 + swz8;
        __syncthreads();
        gload_lds16(gA + k0, sA0);
        gload_lds16(gA + (size_t)8 * 2304 + k0, sA0 + 512);
#pragma unroll
        for (int r = 0; r < 4; ++r)
            gload_lds16(Xt + bb0[r] + offu, sB0 + r * 512);
        __syncthreads();
#pragma unroll
        for (int h = 0; h < 2; ++h) {
            const int sw = h ? sw1 : sw0;
            short8 a[2], b[4];
#pragma unroll
            for (int i = 0; i < 2; ++i)
                a[i] = *reinterpret_cast<const short8*>(As + (wave_n + i * 16 + l15) * 64 + sw);
#pragma unroll
            for (int j = 0; j < 4; ++j)
                b[j] = *reinterpret_cast<const short8*>(Bs + (wave_m + j * 16 + l15) * 64 + sw);
#pragma unroll
            for (int i = 0; i < 2; ++i)
#pragma unroll
                for (int j = 0; j < 4; ++j)
                    acc[i][j] = __builtin_amdgcn_mfma_f32_16x16x32_bf16(a[i], b[j], acc[i][j], 0, 0, 0);
        }
    }
#pragma unroll
    for (int i = 0; i < 2; ++i)
#pragma unroll
        for (int jj = 0; jj < 4; ++jj)
#pragma unroll
            for (int rg = 0; rg < 4; ++rg) {
                const int n = n0 + wave_n + i * 16 + quad * 4 + rg;
                const int m = m0 + wave_m + jj * 16 + l15;
                const float v = acc[i][jj][rg];
                const int bb = m >> 10, p = m & 1023;
                if (n < 256) {
                    out[(size_t)bb * 524288 + (size_t)n * 1024 + p] = v + bias_a[n];
                } else {
                    const int c = n - 256;
                    const float vq = v + bias_b[c];
                    if (c < 256) {
                        const int h = c >> 5, d = c & 31;
                        qT[(((size_t)(bb * 8 + h)) * 1024 + p) * 32 + d] =
                            f2bf(vq * 0.17677669529663687f);
                    } else if (c < 512) {
                        const int c2 = c - 256;
                        const int h = c2 >> 5, d = c2 & 31;
                        kT[(((size_t)(bb * 8 + h)) * 1024 + p) * 32 + d] = f2bf(vq);
                    } else {
                        const int c2 = c - 512;
                        const int h = c2 >> 5, d = c2 & 31;
                        vT[(((size_t)(bb * 8 + h)) * 32 + d) * 1024 + p] = f2bf(vq);
                    }
                }
            }
}

// --------------- MFMA flash attention v4 -------------------------------------
// Grid: bid = qt*64 + bh  =>  bid%8 = bh%8: all 16 q-tiles of one (b,h) on one
// XCD, K/V (128 KB/bh) L2-resident. No online max (logits << 88; fp32-safe).
// Software pipeline per iter nt: QK(nt+1) -> read P(nt) [buf nt&1, written a
// full iter ago] -> exp/pack/write P(nt+1) [buf ~nt&1] -> PV(nt).
__global__ __launch_bounds__(256, 4) void k_attn(const unsigned short* __restrict__ qT,
                                                 const unsigned short* __restrict__ kT,
                                                 const unsigned short* __restrict__ vT,
                                                 const unsigned short* __restrict__ krwb,
                                                 const unsigned short* __restrict__ krhb,
                                                 unsigned short* __restrict__ attT) {
    __shared__ float rh_s[64 * 68];            // [q_local][m'] stride 68 fp32
    __shared__ unsigned short Pw[8 * 1152];    // per-wave double buffer
    const int tid = threadIdx.x;
    const int lane = tid & 63, wv = tid >> 6;
    const int l15 = lane & 15, quad = lane >> 4;
    const int bid = blockIdx.x;
    const int bh = bid & 63;                   // XCD swizzle: bid%8 == bh%8
    const int qt = bid >> 6;
    const int h = bh & 7;
    const int b = bh >> 3;
    const unsigned short* qbase = qT + (size_t)bh * 32768;
    const unsigned short* kbase = kT + (size_t)bh * 32768;
    const unsigned short* vbase = vT + (size_t)bh * 32768;
    const int qloc = wv * 16 + l15;
    const int pq = qt * 64 + qloc;
    const int yq = pq >> 5, xq = pq & 31;

    const short8 qfrag = *reinterpret_cast<const short8*>(
        qbase + (size_t)pq * 32 + quad * 8);
    const floatx4 zero = {0.f, 0.f, 0.f, 0.f};
    unsigned short* pw0 = Pw + wv * 1152;          // buffer 0
    unsigned short* pw1 = Pw + 4608 + wv * 1152;   // buffer 1

    // rel tables via mfma: Rel[m'][q] = krX[m'] . Q[q]
#pragma unroll
    for (int sub = 0; sub < 4; ++sub) {
        const short8 aw = *reinterpret_cast<const short8*>(krwb + (sub * 16 + l15) * 32 + quad * 8);
        const short8 ah = *reinterpret_cast<const short8*>(krhb + (sub * 16 + l15) * 32 + quad * 8);
        const floatx4 dw = __builtin_amdgcn_mfma_f32_16x16x32_bf16(aw, qfrag, zero, 0, 0, 0);
        const floatx4 dh = __builtin_amdgcn_mfma_f32_16x16x32_bf16(ah, qfrag, zero, 0, 0, 0);
        *reinterpret_cast<floatx4*>(rh_s + qloc * 68 + sub * 16 + quad * 4) = dh;
        uint2 uu;
        uu.x = pk2bf_rne(dw[0], dw[1]);
        uu.y = pk2bf_rne(dw[2], dw[3]);
        *reinterpret_cast<uint2*>(pw0 + l15 * 64 + sub * 16 + quad * 4) = uu;
    }
    // per-lane rel_w registers: xn pattern repeats with period 32
    float rwreg[8];
#pragma unroll
    for (int j = 0; j < 8; ++j) {
        const int xn = (j >> 2) * 16 + quad * 4 + (j & 3);
        rwreg[j] = bf2f(pw0[l15 * 64 + xn - xq + 31]);
    }
    asm volatile("s_waitcnt lgkmcnt(0)" ::: "memory");  // pw0 safe to reuse

    const float* rhq = rh_s + qloc * 68 + 31 - yq;
    float lsum = 0.f;
    floatx4 O0 = zero, O1 = zero;              // O[d][q]: d=quad*4+r (+16), q=l15

    short8 kf[4], vf[4];
#pragma unroll
    for (int sub = 0; sub < 4; ++sub)
        kf[sub] = *reinterpret_cast<const short8*>(
            kbase + (size_t)(sub * 16 + l15) * 32 + quad * 8);
#pragma unroll
    for (int n2 = 0; n2 < 2; ++n2) {
        vf[n2 * 2 + 0] = *reinterpret_cast<const short8*>(
            vbase + (size_t)l15 * 1024 + n2 * 32 + quad * 8);
        vf[n2 * 2 + 1] = *reinterpret_cast<const short8*>(
            vbase + (size_t)(16 + l15) * 1024 + n2 * 32 + quad * 8);
    }
    // prologue: P(0) -> buf0
    {
        floatx4 d[4];
#pragma unroll
        for (int sub = 0; sub < 4; ++sub)
            d[sub] = __builtin_amdgcn_mfma_f32_16x16x32_bf16(kf[sub], qfrag, zero, 0, 0, 0);
        const float rh0 = rhq[0], rh1 = rhq[1];
#pragma unroll
        for (int sub = 0; sub < 4; ++sub) {
            const float rhv = (sub >> 1) ? rh1 : rh0;
            float p[4];
#pragma unroll
            for (int r = 0; r < 4; ++r) {
                p[r] = __expf(d[sub][r] + rwreg[(sub & 1) * 4 + r] + rhv);
                lsum += p[r];
            }
            uint2 uu;
            uu.x = pk2bf_trunc(p[0], p[1]);
            uu.y = pk2bf_trunc(p[2], p[3]);
            *reinterpret_cast<uint2*>(pw0 + l15 * 72 + sub * 16 + quad * 4) = uu;
        }
        // load K(1)
#pragma unroll
        for (int sub = 0; sub < 4; ++sub)
            kf[sub] = *reinterpret_cast<const short8*>(
                kbase + (size_t)(64 + sub * 16 + l15) * 32 + quad * 8);
    }

#pragma unroll
    for (int nt = 0; nt < 16; ++nt) {
        unsigned short* pwr = (nt & 1) ? pw1 : pw0;   // P(nt)
        unsigned short* pww = (nt & 1) ? pw0 : pw1;   // P(nt+1)
        // 1. QK(nt+1)
        floatx4 d[4];
        if (nt < 15) {
#pragma unroll
            for (int sub = 0; sub < 4; ++sub)
                d[sub] = __builtin_amdgcn_mfma_f32_16x16x32_bf16(kf[sub], qfrag, zero, 0, 0, 0);
        }
        // 2. read P(nt) (write was a full iteration ago -> wait is ~free)
        asm volatile("s_waitcnt lgkmcnt(0)" ::: "memory");
        short8 pfrag[2];
#pragma unroll
        for (int n2 = 0; n2 < 2; ++n2)
            pfrag[n2] = *reinterpret_cast<const short8*>(
                pwr + l15 * 72 + n2 * 32 + quad * 8);
        // 3. exp/pack/write P(nt+1)
        if (nt < 15) {
            const float rh0 = rhq[(nt + 1) * 2], rh1 = rhq[(nt + 1) * 2 + 1];
#pragma unroll
            for (int sub = 0; sub < 4; ++sub) {
                const float rhv = (sub >> 1) ? rh1 : rh0;
                float p[4];
#pragma unroll
                for (int r = 0; r < 4; ++r) {
                    p[r] = __expf(d[sub][r] + rwreg[(sub & 1) * 4 + r] + rhv);
                    lsum += p[r];
                }
                uint2 uu;
                uu.x = pk2bf_trunc(p[0], p[1]);
                uu.y = pk2bf_trunc(p[2], p[3]);
                *reinterpret_cast<uint2*>(pww + l15 * 72 + sub * 16 + quad * 4) = uu;
            }
        }
        // 4. PV(nt) with vf = V(nt)
        O0 = __builtin_amdgcn_mfma_f32_16x16x32_bf16(vf[0], pfrag[0], O0, 0, 0, 0);
        O1 = __builtin_amdgcn_mfma_f32_16x16x32_bf16(vf[1], pfrag[0], O1, 0, 0, 0);
        O0 = __builtin_amdgcn_mfma_f32_16x16x32_bf16(vf[2], pfrag[1], O0, 0, 0, 0);
        O1 = __builtin_amdgcn_mfma_f32_16x16x32_bf16(vf[3], pfrag[1], O1, 0, 0, 0);
        // 5. prefetch K(nt+2), V(nt+1)
        if (nt < 14) {
            const int nk = (nt + 2) * 64;
#pragma unroll
            for (int sub = 0; sub < 4; ++sub)
                kf[sub] = *reinterpret_cast<const short8*>(
                    kbase + (size_t)(nk + sub * 16 + l15) * 32 + quad * 8);
        }
        if (nt < 15) {
            const int nv = (nt + 1) * 64;
            vf[0] = *reinterpret_cast<const short8*>(
                vbase + (size_t)l15 * 1024 + nv + quad * 8);
            vf[1] = *reinterpret_cast<const short8*>(
                vbase + (size_t)(16 + l15) * 1024 + nv + quad * 8);
            vf[2] = *reinterpret_cast<const short8*>(
                vbase + (size_t)l15 * 1024 + nv + 32 + quad * 8);
            vf[3] = *reinterpret_cast<const short8*>(
                vbase + (size_t)(16 + l15) * 1024 + nv + 32 + quad * 8);
        }
    }
    lsum += __shfl_xor(lsum, 16);
    lsum += __shfl_xor(lsum, 32);
    const float inv = 1.0f / lsum;
    // coalesced output: attT[ci=h*32+yq][m2=b*1024+xq*32+d]
    unsigned short* ob = attT + ((size_t)(h * 32 + yq)) * 8192 + b * 1024 + xq * 32;
    uint2 o0, o1;
    o0.x = pk2bf_rne(O0[0] * inv, O0[1] * inv);
    o0.y = pk2bf_rne(O0[2] * inv, O0[3] * inv);
    o1.x = pk2bf_rne(O1[0] * inv, O1[1] * inv);
    o1.y = pk2bf_rne(O1[2] * inv, O1[3] * inv);
    *reinterpret_cast<uint2*>(ob + quad * 4) = o0;
    *reinterpret_cast<uint2*>(ob + 16 + quad * 4) = o1;
}

// --------------- attT [256][8192] -> attt [8192][256] -----------------------
__global__ __launch_bounds__(256) void k_tr(const unsigned short* __restrict__ src,
                                            unsigned short* __restrict__ dst) {
    __shared__ unsigned short t[64 * 72];
    const int tid = threadIdx.x;
    const int m0 = (blockIdx.x & 127) * 64;
    const int k0 = (blockIdx.x >> 7) * 64;
#pragma unroll
    for (int i = 0; i < 2; ++i) {
        const int idx = i * 256 + tid;
        const int k = idx >> 3, c8 = (idx & 7) * 8;
        *reinterpret_cast<uint4*>(t + k * 72 + c8) =
            *reinterpret_cast<const uint4*>(src + (size_t)(k0 + k) * 8192 + m0 + c8);
    }
    __syncthreads();
#pragma unroll
    for (int i = 0; i < 2; ++i) {
        const int idx = i * 256 + tid;
        const int m = idx >> 3, c8 = (idx & 7) * 8;
        unsigned short v[8];
#pragma unroll
        for (int j = 0; j < 8; ++j) v[j] = t[(c8 + j) * 72 + m];
        *reinterpret_cast<uint4*>(dst + (size_t)(m0 + m) * 256 + k0 + c8) =
            *reinterpret_cast<uint4*>(v);
    }
}

// --------------- small 64-tile GEMM for the 1x1 conv ------------------------
__global__ __launch_bounds__(256) void k_gemm_s(const unsigned short* __restrict__ Wm,
                                                const unsigned short* __restrict__ Dm,
                                                float* __restrict__ out,
                                                const float* __restrict__ bias) {
    __shared__ unsigned short As[64 * 40];
    __shared__ unsigned short Bs[64 * 40];
    const int tid = threadIdx.x;
    const int m0 = blockIdx.x * 64, n0 = blockIdx.y * 64;
    const int lane = tid & 63;
    const int wv = tid >> 6;
    const int l15 = lane & 15, quad = lane >> 4;
    const int n_off = (wv & 1) * 32, m_off = (wv >> 1) * 32;
    floatx4 acc[2][2] = {};
    const int r = tid >> 2, c8 = (tid & 3) * 8;
    const unsigned short* gA = Wm + (size_t)(n0 + r) * 256 + c8;
    const unsigned short* gB = Dm + (size_t)(m0 + r) * 256 + c8;
    unsigned short* sA = As + r * 40 + c8;
    unsigned short* sB = Bs + r * 40 + c8;
    for (int k0 = 0; k0 < 256; k0 += 32) {
        __syncthreads();
        *reinterpret_cast<uint4*>(sA) = *reinterpret_cast<const uint4*>(gA + k0);
        *reinterpret_cast<uint4*>(sB) = *reinterpret_cast<const uint4*>(gB + k0);
        __syncthreads();
        const short8 a0 = *reinterpret_cast<const short8*>(As + (n_off +      l15) * 40 + quad * 8);
        const short8 a1 = *reinterpret_cast<const short8*>(As + (n_off + 16 + l15) * 40 + quad * 8);
        const short8 b0 = *reinterpret_cast<const short8*>(Bs + (m_off +      l15) * 40 + quad * 8);
        const short8 b1 = *reinterpret_cast<const short8*>(Bs + (m_off + 16 + l15) * 40 + quad * 8);
        acc[0][0] = __builtin_amdgcn_mfma_f32_16x16x32_bf16(a0, b0, acc[0][0], 0, 0, 0);
        acc[0][1] = __builtin_amdgcn_mfma_f32_16x16x32_bf16(a0, b1, acc[0][1], 0, 0, 0);
        acc[1][0] = __builtin_amdgcn_mfma_f32_16x16x32_bf16(a1, b0, acc[1][0], 0, 0, 0);
        acc[1][1] = __builtin_amdgcn_mfma_f32_16x16x32_bf16(a1, b1, acc[1][1], 0, 0, 0);
    }
#pragma unroll
    for (int i = 0; i < 2; ++i)
#pragma unroll
        for (int jj = 0; jj < 2; ++jj)
#pragma unroll
            for (int rg = 0; rg < 4; ++rg) {
                const int n = n0 + n_off + i * 16 + quad * 4 + rg;
                const int m = m0 + m_off + jj * 16 + l15;
                const int bb = m >> 10, p = m & 1023;
                out[(size_t)bb * 524288 + (size_t)(n + 256) * 1024 + p] =
                    acc[i][jj][rg] + bias[n];
            }
}

// ---------------------------------------------------------------------------
extern "C" void kernel_launch(void* const* d_in, const int* in_sizes, int n_in,
                              void* d_out, int out_size, void* d_ws, size_t ws_size,
                              hipStream_t stream) {
    const float* x      = (const float*)d_in[0];
    const float* w_conv = (const float*)d_in[1];
    const float* b_conv = (const float*)d_in[2];
    const float* w_qkv  = (const float*)d_in[3];
    const float* b_qkv  = (const float*)d_in[4];
    const float* w_att  = (const float*)d_in[5];
    const float* b_att  = (const float*)d_in[6];
    const float* krw    = (const float*)d_in[7];
    const float* krh    = (const float*)d_in[8];
    float* out = (float*)d_out;

    char* ws = (char*)d_ws;
    unsigned short* Xt    = (unsigned short*)(ws);              //  4,734,976 B
    unsigned short* wt    = (unsigned short*)(ws + 9470464);    //  4,718,592 B
    unsigned short* wt2   = (unsigned short*)(ws + 14189056);   //    131,072 B
    unsigned short* qT    = (unsigned short*)(ws + 14320128);   //  4,194,304 B
    unsigned short* kT    = (unsigned short*)(ws + 18514432);   //  4,194,304 B
    unsigned short* vT    = (unsigned short*)(ws + 22708736);   //  4,194,304 B
    unsigned short* attt  = (unsigned short*)(ws + 26903040);   //  4,194,304 B
    unsigned short* krwb  = (unsigned short*)(ws + 31097344);   //      4,096 B
    unsigned short* krhb  = (unsigned short*)(ws + 31101440);   //      4,096 B
    unsigned short* attTT = (unsigned short*)(ws + 31105536);   //  4,194,304 B

    k_xt<<<dim3(272), dim3(256), 0, stream>>>(x, Xt);
    k_wconv<<<dim3(1296), dim3(256), 0, stream>>>(w_conv, w_qkv, w_att, krw, krh,
                                                  wt, wt2, krwb, krhb);
    k_gemm0<<<dim3(64, 16), dim3(256), 0, stream>>>(wt, Xt, out, qT, kT, vT,
                                                    b_conv, b_qkv);
    k_attn<<<dim3(1024), dim3(256), 0, stream>>>(qT, kT, vT, krwb, krhb, attTT);
    k_tr<<<dim3(512), dim3(256), 0, stream>>>(attTT, attt);
    k_gemm_s<<<dim3(128, 4), dim3(256), 0, stream>>>(wt2, attt, out, b_att);
}

// Round 8
// 196.479 us; speedup vs baseline: 1.4637x; 1.4637x over previous
//
#include <hip/hip_runtime.h>

// ---------------------------------------------------------------------------
// AttentionAugmentedConv2d: B=8, CIN=256, COUT=512, DK=DV=256, NH=8, H=W=32
//  k_xt     : x (fp32) -> padded transposed Xt[b][yy:34][xx:34][ci:256] bf16
//  k_wconv  : weights -> bf16, K reordered to k'=(ky*3+kx)*256+ci (wt)
//  k_gemm0  : implicit-GEMM fused conv (128M x 64N, BK=64, 1024 blocks)
//  k_attn   : MFMA flash attention v3 + XCD swizzle (bid = qt*64+bh so all 16
//             q-tiles of one (b,h) share an XCD; K/V L2-resident). No online
//             max (logits << 88, fp32-safe). NOTE: v4's deeper software
//             pipeline SPILLED (VGPR 64 cap -> 191 MB scratch writes) - keep
//             the v3 register footprint.
//  k_tr     : attT [256][8192] -> attt [8192][256]
//  k_gemm_s : 1x1 conv GEMM -> out ch 256..511
// reshape trap: att channel = h*32 + y, spatial = (x, d)
// ---------------------------------------------------------------------------

typedef __attribute__((ext_vector_type(8))) short short8;
typedef __attribute__((ext_vector_type(4))) float floatx4;

__device__ __forceinline__ unsigned short f2bf(float f) {
    unsigned int u = __float_as_uint(f);
    u += 0x7FFFu + ((u >> 16) & 1u);   // round-to-nearest-even
    return (unsigned short)(u >> 16);
}
__device__ __forceinline__ float bf2f(unsigned short s) {
    return __uint_as_float(((unsigned int)s) << 16);
}
__device__ __forceinline__ unsigned int pk2bf_trunc(float lo, float hi) {
    return (__float_as_uint(lo) >> 16) | (__float_as_uint(hi) & 0xFFFF0000u);
}
__device__ __forceinline__ unsigned int pk2bf_rne(float lo, float hi) {
    return (unsigned int)f2bf(lo) | ((unsigned int)f2bf(hi) << 16);
}
__device__ __forceinline__ void gload_lds16(const unsigned short* g, unsigned short* s) {
    __builtin_amdgcn_global_load_lds(
        (const __attribute__((address_space(1))) unsigned int*)g,
        (__attribute__((address_space(3))) unsigned int*)s, 16, 0, 0);
}

// ---------------- Xt: padded transpose -------------------------------------
__global__ __launch_bounds__(256) void k_xt(const float* __restrict__ x,
                                            unsigned short* __restrict__ Xt) {
    __shared__ unsigned short lds[256 * 33];
    const int tid = threadIdx.x;
    const int yy = blockIdx.x % 34;
    const int b  = blockIdx.x / 34;
    unsigned int* outp = (unsigned int*)(Xt + (((size_t)b * 34 + yy) * 34) * 256);
    if (yy == 0 || yy == 33) {
        for (int i = tid; i < 4352; i += 256) outp[i] = 0;
        return;
    }
    const int y = yy - 1;
    const float* xb = x + (size_t)b * 262144 + y * 32;
#pragma unroll
    for (int it = 0; it < 32; ++it) {
        const int e = it * 256 + tid;
        const int ci = e >> 5, xx = e & 31;
        lds[ci * 33 + xx] = f2bf(xb[ci * 1024 + xx]);
    }
    __syncthreads();
    const int ci2 = (tid & 127) * 2;
    const int xh = tid >> 7;
#pragma unroll
    for (int it = 0; it < 17; ++it) {
        const int xx = xh * 17 + it;
        unsigned int v = 0;
        if (xx >= 1 && xx <= 32)
            v = (unsigned int)lds[ci2 * 33 + xx - 1] |
                ((unsigned int)lds[(ci2 + 1) * 33 + xx - 1] << 16);
        outp[xx * 128 + (tid & 127)] = v;
    }
}

// --------------- weight convert + K reorder, LDS-staged ---------------------
__global__ __launch_bounds__(256) void k_wconv(const float* __restrict__ wc,
                                               const float* __restrict__ wq,
                                               const float* __restrict__ wa,
                                               const float* __restrict__ krw,
                                               const float* __restrict__ krh,
                                               unsigned short* __restrict__ wt,
                                               unsigned short* __restrict__ wt2,
                                               unsigned short* __restrict__ krwb,
                                               unsigned short* __restrict__ krhb) {
    const int tid = threadIdx.x;
    const int blk = blockIdx.x;
    if (blk < 1024) {
        __shared__ float lw[2304];
        const int n = blk;
        const float* src = (n < 256) ? (wc + (size_t)n * 2304)
                                     : (wq + (size_t)(n - 256) * 2304);
#pragma unroll
        for (int it = 0; it < 9; ++it)
            lw[it * 256 + tid] = src[it * 256 + tid];
        __syncthreads();
#pragma unroll
        for (int it = 0; it < 9; ++it) {
            const int kp = it * 256 + tid;
            const int g = kp >> 8, ci = kp & 255;
            wt[(size_t)n * 2304 + kp] = f2bf(lw[ci * 9 + g]);
        }
    } else {
        const int i = (blk - 1024) * 256 + tid;
        if (i < 65536)        wt2[i] = f2bf(wa[i]);
        else if (i < 67584) { const int j = i - 65536;
                              krwb[j] = (j < 2016) ? f2bf(krw[j]) : (unsigned short)0; }
        else if (i < 69632) { const int j = i - 67584;
                              krhb[j] = (j < 2016) ? f2bf(krh[j]) : (unsigned short)0; }
    }
}

// --------------- implicit-GEMM fused conv, 128M x 64N, BK=64 ----------------
__global__ __launch_bounds__(256, 4) void k_gemm0(const unsigned short* __restrict__ Wr,
                                                  const unsigned short* __restrict__ Xt,
                                                  float* __restrict__ out,
                                                  unsigned short* __restrict__ qT,
                                                  unsigned short* __restrict__ kT,
                                                  unsigned short* __restrict__ vT,
                                                  const float* __restrict__ bias_a,
                                                  const float* __restrict__ bias_b) {
    __shared__ unsigned short As[64 * 64];
    __shared__ unsigned short Bs[128 * 64];
    const int tid = threadIdx.x;
    const int lane = tid & 63, wv = tid >> 6;
    const int l15 = lane & 15, quad = lane >> 4;
    const int m0 = blockIdx.x * 128, n0 = blockIdx.y * 64;
    const int wave_m = (wv & 1) * 64, wave_n = (wv >> 1) * 32;
    floatx4 acc[2][4] = {};
    const int lr = lane >> 3;
    const int swz8 = ((lane & 7) ^ lr) * 8;
    const unsigned short* gA = Wr + (size_t)(n0 + wv * 16 + lr) * 2304 + swz8;
    int bb0[4];
#pragma unroll
    for (int r = 0; r < 4; ++r) {
        const int m = m0 + wv * 32 + r * 8 + lr;
        const int b = m >> 10, p = m & 1023, y = p >> 5, x = p & 31;
        bb0[r] = ((b * 34 + y) * 34 + x) * 256;
    }
    unsigned short* sA0 = As + wv * 1024;
    unsigned short* sB0 = Bs + wv * 2048;
    const int sw0 = ((quad)     ^ (l15 & 7)) * 8;
    const int sw1 = ((4 + quad) ^ (l15 & 7)) * 8;
    for (int k0 = 0; k0 < 2304; k0 += 64) {
        const int g = k0 >> 8;
        const int ci0 = k0 & 255;
        const int ky = g / 3, kx = g - ky * 3;
        const int offu = (ky * 34 + kx) * 256 + ci0 + swz8;
        __syncthreads();
        gload_lds16(gA + k0, sA0);
        gload_lds16(gA + (size_t)8 * 2304 + k0, sA0 + 512);
#pragma unroll
        for (int r = 0; r < 4; ++r)
            gload_lds16(Xt + bb0[r] + offu, sB0 + r * 512);
        __syncthreads();
#pragma unroll
        for (int h = 0; h < 2; ++h) {
            const int sw = h ? sw1 : sw0;
            short8 a[2], b[4];
#pragma unroll
            for (int i = 0; i < 2; ++i)
                a[i] = *reinterpret_cast<const short8*>(As + (wave_n + i * 16 + l15) * 64 + sw);
#pragma unroll
            for (int j = 0; j < 4; ++j)
                b[j] = *reinterpret_cast<const short8*>(Bs + (wave_m + j * 16 + l15) * 64 + sw);
#pragma unroll
            for (int i = 0; i < 2; ++i)
#pragma unroll
                for (int j = 0; j < 4; ++j)
                    acc[i][j] = __builtin_amdgcn_mfma_f32_16x16x32_bf16(a[i], b[j], acc[i][j], 0, 0, 0);
        }
    }
#pragma unroll
    for (int i = 0; i < 2; ++i)
#pragma unroll
        for (int jj = 0; jj < 4; ++jj)
#pragma unroll
            for (int rg = 0; rg < 4; ++rg) {
                const int n = n0 + wave_n + i * 16 + quad * 4 + rg;
                const int m = m0 + wave_m + jj * 16 + l15;
                const float v = acc[i][jj][rg];
                const int bb = m >> 10, p = m & 1023;
                if (n < 256) {
                    out[(size_t)bb * 524288 + (size_t)n * 1024 + p] = v + bias_a[n];
                } else {
                    const int c = n - 256;
                    const float vq = v + bias_b[c];
                    if (c < 256) {
                        const int h = c >> 5, d = c & 31;
                        qT[(((size_t)(bb * 8 + h)) * 1024 + p) * 32 + d] =
                            f2bf(vq * 0.17677669529663687f);
                    } else if (c < 512) {
                        const int c2 = c - 256;
                        const int h = c2 >> 5, d = c2 & 31;
                        kT[(((size_t)(bb * 8 + h)) * 1024 + p) * 32 + d] = f2bf(vq);
                    } else {
                        const int c2 = c - 512;
                        const int h = c2 >> 5, d = c2 & 31;
                        vT[(((size_t)(bb * 8 + h)) * 32 + d) * 1024 + p] = f2bf(vq);
                    }
                }
            }
}

// --------------- MFMA flash attention v3 + XCD swizzle ----------------------
// bid = qt*64 + bh  =>  bid%8 = h: all 16 q-tiles of one (b,h) on one XCD,
// K/V (128 KB/bh) L2-resident. No online max (logits << 88; fp32-safe).
// mfma: D[i][j]=sum_k A[i][k]B[j][k]; frag lane holds X[l15][quad*8+:8];
// D lane holds D[quad*4+r][l15].
__global__ __launch_bounds__(256, 4) void k_attn(const unsigned short* __restrict__ qT,
                                                 const unsigned short* __restrict__ kT,
                                                 const unsigned short* __restrict__ vT,
                                                 const unsigned short* __restrict__ krwb,
                                                 const unsigned short* __restrict__ krhb,
                                                 unsigned short* __restrict__ attT) {
    __shared__ float rh_s[64 * 68];            // [q_local][m'] stride 68 fp32
    __shared__ unsigned short Pw[4 * 1152];    // per-wave: rw staging, then P
    const int tid = threadIdx.x;
    const int lane = tid & 63, wv = tid >> 6;
    const int l15 = lane & 15, quad = lane >> 4;
    const int bid = blockIdx.x;
    const int bh = bid & 63;                   // XCD swizzle: bid%8 == h
    const int qt = bid >> 6;
    const int h = bh & 7;
    const int b = bh >> 3;
    const unsigned short* qbase = qT + (size_t)bh * 32768;
    const unsigned short* kbase = kT + (size_t)bh * 32768;
    const unsigned short* vbase = vT + (size_t)bh * 32768;
    const int qloc = wv * 16 + l15;
    const int pq = qt * 64 + qloc;
    const int yq = pq >> 5, xq = pq & 31;

    const short8 qfrag = *reinterpret_cast<const short8*>(
        qbase + (size_t)pq * 32 + quad * 8);
    const floatx4 zero = {0.f, 0.f, 0.f, 0.f};
    unsigned short* pw = Pw + wv * 1152;

    // rel tables via mfma: Rel[m'][q] = krX[m'] . Q[q]
#pragma unroll
    for (int sub = 0; sub < 4; ++sub) {
        const short8 aw = *reinterpret_cast<const short8*>(krwb + (sub * 16 + l15) * 32 + quad * 8);
        const short8 ah = *reinterpret_cast<const short8*>(krhb + (sub * 16 + l15) * 32 + quad * 8);
        const floatx4 dw = __builtin_amdgcn_mfma_f32_16x16x32_bf16(aw, qfrag, zero, 0, 0, 0);
        const floatx4 dh = __builtin_amdgcn_mfma_f32_16x16x32_bf16(ah, qfrag, zero, 0, 0, 0);
        *reinterpret_cast<floatx4*>(rh_s + qloc * 68 + sub * 16 + quad * 4) = dh;
        uint2 uu;
        uu.x = pk2bf_rne(dw[0], dw[1]);
        uu.y = pk2bf_rne(dw[2], dw[3]);
        *reinterpret_cast<uint2*>(pw + l15 * 64 + sub * 16 + quad * 4) = uu;
    }
    // per-lane rel_w registers: xn pattern repeats with period 32
    float rwreg[8];
#pragma unroll
    for (int j = 0; j < 8; ++j) {
        const int xn = (j >> 2) * 16 + quad * 4 + (j & 3);
        rwreg[j] = bf2f(pw[l15 * 64 + xn - xq + 31]);
    }
    asm volatile("s_waitcnt lgkmcnt(0)" ::: "memory");  // pw safe to reuse for P

    const float* rhq = rh_s + qloc * 68 + 31 - yq;
    float lsum = 0.f;
    floatx4 O0 = zero, O1 = zero;              // O[d][q]: d=quad*4+r (+16), q=l15

    short8 kf[4], vf[4];
#pragma unroll
    for (int sub = 0; sub < 4; ++sub)
        kf[sub] = *reinterpret_cast<const short8*>(
            kbase + (size_t)(sub * 16 + l15) * 32 + quad * 8);
#pragma unroll
    for (int n2 = 0; n2 < 2; ++n2) {
        vf[n2 * 2 + 0] = *reinterpret_cast<const short8*>(
            vbase + (size_t)l15 * 1024 + n2 * 32 + quad * 8);
        vf[n2 * 2 + 1] = *reinterpret_cast<const short8*>(
            vbase + (size_t)(16 + l15) * 1024 + n2 * 32 + quad * 8);
    }

#pragma unroll
    for (int nt = 0; nt < 16; ++nt) {
        const int n0 = nt * 64;
        const int n0n = (nt < 15) ? n0 + 64 : n0;
        // QK^T
        floatx4 d[4];
#pragma unroll
        for (int sub = 0; sub < 4; ++sub)
            d[sub] = __builtin_amdgcn_mfma_f32_16x16x32_bf16(kf[sub], qfrag, zero, 0, 0, 0);
        // prefetch next K tile
        short8 kfn[4], vfn[4];
#pragma unroll
        for (int sub = 0; sub < 4; ++sub)
            kfn[sub] = *reinterpret_cast<const short8*>(
                kbase + (size_t)(n0n + sub * 16 + l15) * 32 + quad * 8);
        const float rh0 = rhq[nt * 2];
        const float rh1 = rhq[nt * 2 + 1];
        // p = exp(score); no max subtraction; per-lane l accumulation
        float p[16];
#pragma unroll
        for (int sub = 0; sub < 4; ++sub) {
            const float rhv = (sub >> 1) ? rh1 : rh0;
#pragma unroll
            for (int r = 0; r < 4; ++r) {
                const float e = __expf(d[sub][r] + rwreg[(sub & 1) * 4 + r] + rhv);
                p[sub * 4 + r] = e;
                lsum += e;
            }
        }
        // write P (row q=l15, cols quad*4+r per subtile), truncating bf16
#pragma unroll
        for (int sub = 0; sub < 4; ++sub) {
            uint2 uu;
            uu.x = pk2bf_trunc(p[sub * 4 + 0], p[sub * 4 + 1]);
            uu.y = pk2bf_trunc(p[sub * 4 + 2], p[sub * 4 + 3]);
            *reinterpret_cast<uint2*>(pw + l15 * 72 + sub * 16 + quad * 4) = uu;
        }
        asm volatile("s_waitcnt lgkmcnt(0)" ::: "memory");
        // PV: O[d][q] += sum_n V^T[d][n] P[q][n]
#pragma unroll
        for (int n2 = 0; n2 < 2; ++n2) {
            const short8 pfrag = *reinterpret_cast<const short8*>(
                pw + l15 * 72 + n2 * 32 + quad * 8);
            O0 = __builtin_amdgcn_mfma_f32_16x16x32_bf16(vf[n2 * 2 + 0], pfrag, O0, 0, 0, 0);
            O1 = __builtin_amdgcn_mfma_f32_16x16x32_bf16(vf[n2 * 2 + 1], pfrag, O1, 0, 0, 0);
        }
        // prefetch next V tile
#pragma unroll
        for (int n2 = 0; n2 < 2; ++n2) {
            vfn[n2 * 2 + 0] = *reinterpret_cast<const short8*>(
                vbase + (size_t)l15 * 1024 + n0n + n2 * 32 + quad * 8);
            vfn[n2 * 2 + 1] = *reinterpret_cast<const short8*>(
                vbase + (size_t)(16 + l15) * 1024 + n0n + n2 * 32 + quad * 8);
        }
#pragma unroll
        for (int i = 0; i < 4; ++i) { kf[i] = kfn[i]; vf[i] = vfn[i]; }
    }
    // l: reduce across quads (lane bits 4,5)
    lsum += __shfl_xor(lsum, 16);
    lsum += __shfl_xor(lsum, 32);
    const float inv = 1.0f / lsum;
    // coalesced output: attT[ci=h*32+yq][m2=b*1024+xq*32+d]
    unsigned short* ob = attT + ((size_t)(h * 32 + yq)) * 8192 + b * 1024 + xq * 32;
    uint2 o0, o1;
    o0.x = pk2bf_rne(O0[0] * inv, O0[1] * inv);
    o0.y = pk2bf_rne(O0[2] * inv, O0[3] * inv);
    o1.x = pk2bf_rne(O1[0] * inv, O1[1] * inv);
    o1.y = pk2bf_rne(O1[2] * inv, O1[3] * inv);
    *reinterpret_cast<uint2*>(ob + quad * 4) = o0;
    *reinterpret_cast<uint2*>(ob + 16 + quad * 4) = o1;
}

// --------------- attT [256][8192] -> attt [8192][256] -----------------------
__global__ __launch_bounds__(256) void k_tr(const unsigned short* __restrict__ src,
                                            unsigned short* __restrict__ dst) {
    __shared__ unsigned short t[64 * 72];
    const int tid = threadIdx.x;
    const int m0 = (blockIdx.x & 127) * 64;
    const int k0 = (blockIdx.x >> 7) * 64;
#pragma unroll
    for (int i = 0; i < 2; ++i) {
        const int idx = i * 256 + tid;
        const int k = idx >> 3, c8 = (idx & 7) * 8;
        *reinterpret_cast<uint4*>(t + k * 72 + c8) =
            *reinterpret_cast<const uint4*>(src + (size_t)(k0 + k) * 8192 + m0 + c8);
    }
    __syncthreads();
#pragma unroll
    for (int i = 0; i < 2; ++i) {
        const int idx = i * 256 + tid;
        const int m = idx >> 3, c8 = (idx & 7) * 8;
        unsigned short v[8];
#pragma unroll
        for (int j = 0; j < 8; ++j) v[j] = t[(c8 + j) * 72 + m];
        *reinterpret_cast<uint4*>(dst + (size_t)(m0 + m) * 256 + k0 + c8) =
            *reinterpret_cast<uint4*>(v);
    }
}

// --------------- small 64-tile GEMM for the 1x1 conv ------------------------
__global__ __launch_bounds__(256) void k_gemm_s(const unsigned short* __restrict__ Wm,
                                                const unsigned short* __restrict__ Dm,
                                                float* __restrict__ out,
                                                const float* __restrict__ bias) {
    __shared__ unsigned short As[64 * 40];
    __shared__ unsigned short Bs[64 * 40];
    const int tid = threadIdx.x;
    const int m0 = blockIdx.x * 64, n0 = blockIdx.y * 64;
    const int lane = tid & 63;
    const int wv = tid >> 6;
    const int l15 = lane & 15, quad = lane >> 4;
    const int n_off = (wv & 1) * 32, m_off = (wv >> 1) * 32;
    floatx4 acc[2][2] = {};
    const int r = tid >> 2, c8 = (tid & 3) * 8;
    const unsigned short* gA = Wm + (size_t)(n0 + r) * 256 + c8;
    const unsigned short* gB = Dm + (size_t)(m0 + r) * 256 + c8;
    unsigned short* sA = As + r * 40 + c8;
    unsigned short* sB = Bs + r * 40 + c8;
    for (int k0 = 0; k0 < 256; k0 += 32) {
        __syncthreads();
        *reinterpret_cast<uint4*>(sA) = *reinterpret_cast<const uint4*>(gA + k0);
        *reinterpret_cast<uint4*>(sB) = *reinterpret_cast<const uint4*>(gB + k0);
        __syncthreads();
        const short8 a0 = *reinterpret_cast<const short8*>(As + (n_off +      l15) * 40 + quad * 8);
        const short8 a1 = *reinterpret_cast<const short8*>(As + (n_off + 16 + l15) * 40 + quad * 8);
        const short8 b0 = *reinterpret_cast<const short8*>(Bs + (m_off +      l15) * 40 + quad * 8);
        const short8 b1 = *reinterpret_cast<const short8*>(Bs + (m_off + 16 + l15) * 40 + quad * 8);
        acc[0][0] = __builtin_amdgcn_mfma_f32_16x16x32_bf16(a0, b0, acc[0][0], 0, 0, 0);
        acc[0][1] = __builtin_amdgcn_mfma_f32_16x16x32_bf16(a0, b1, acc[0][1], 0, 0, 0);
        acc[1][0] = __builtin_amdgcn_mfma_f32_16x16x32_bf16(a1, b0, acc[1][0], 0, 0, 0);
        acc[1][1] = __builtin_amdgcn_mfma_f32_16x16x32_bf16(a1, b1, acc[1][1], 0, 0, 0);
    }
#pragma unroll
    for (int i = 0; i < 2; ++i)
#pragma unroll
        for (int jj = 0; jj < 2; ++jj)
#pragma unroll
            for (int rg = 0; rg < 4; ++rg) {
                const int n = n0 + n_off + i * 16 + quad * 4 + rg;
                const int m = m0 + m_off + jj * 16 + l15;
                const int bb = m >> 10, p = m & 1023;
                out[(size_t)bb * 524288 + (size_t)(n + 256) * 1024 + p] =
                    acc[i][jj][rg] + bias[n];
            }
}

// ---------------------------------------------------------------------------
extern "C" void kernel_launch(void* const* d_in, const int* in_sizes, int n_in,
                              void* d_out, int out_size, void* d_ws, size_t ws_size,
                              hipStream_t stream) {
    const float* x      = (const float*)d_in[0];
    const float* w_conv = (const float*)d_in[1];
    const float* b_conv = (const float*)d_in[2];
    const float* w_qkv  = (const float*)d_in[3];
    const float* b_qkv  = (const float*)d_in[4];
    const float* w_att  = (const float*)d_in[5];
    const float* b_att  = (const float*)d_in[6];
    const float* krw    = (const float*)d_in[7];
    const float* krh    = (const float*)d_in[8];
    float* out = (float*)d_out;

    char* ws = (char*)d_ws;
    unsigned short* Xt    = (unsigned short*)(ws);              //  4,734,976 B
    unsigned short* wt    = (unsigned short*)(ws + 9470464);    //  4,718,592 B
    unsigned short* wt2   = (unsigned short*)(ws + 14189056);   //    131,072 B
    unsigned short* qT    = (unsigned short*)(ws + 14320128);   //  4,194,304 B
    unsigned short* kT    = (unsigned short*)(ws + 18514432);   //  4,194,304 B
    unsigned short* vT    = (unsigned short*)(ws + 22708736);   //  4,194,304 B
    unsigned short* attt  = (unsigned short*)(ws + 26903040);   //  4,194,304 B
    unsigned short* krwb  = (unsigned short*)(ws + 31097344);   //      4,096 B
    unsigned short* krhb  = (unsigned short*)(ws + 31101440);   //      4,096 B
    unsigned short* attTT = (unsigned short*)(ws + 31105536);   //  4,194,304 B

    k_xt<<<dim3(272), dim3(256), 0, stream>>>(x, Xt);
    k_wconv<<<dim3(1296), dim3(256), 0, stream>>>(w_conv, w_qkv, w_att, krw, krh,
                                                  wt, wt2, krwb, krhb);
    k_gemm0<<<dim3(64, 16), dim3(256), 0, stream>>>(wt, Xt, out, qT, kT, vT,
                                                    b_conv, b_qkv);
    k_attn<<<dim3(1024), dim3(256), 0, stream>>>(qT, kT, vT, krwb, krhb, attTT);
    k_tr<<<dim3(512), dim3(256), 0, stream>>>(attTT, attt);
    k_gemm_s<<<dim3(128, 4), dim3(256), 0, stream>>>(wt2, attt, out, b_att);
}